// Round 23
// baseline (247.376 us; speedup 1.0000x reference)
//
#include <hip/hip_runtime.h>
#include <math.h>

// ---- problem constants ----
#define NB   4
#define CINc 256
#define LLEN 1024      // H*W = 32*32
#define NHEAD 8
#define QKVOC 192      // 2*DK + DV
#define CONVOC 192     // COUT - DV
#define OHW  31

// ---- workspace layout ----
// floats:
#define WS_SCALE 0           // 192 floats: conv weight-norm scale
#define WS_STATS 192         // 8 floats: per-batch {mean, rstd}
#define WS_PART  256         // 4096*2 floats: per-block conv partial {sum,sumsq}
#define WS_QKV   8448        // 4*192*1024 = 786432 floats
#define WS_E     794880      // 4*8*1024*8 = 262144 floats -> end 1057024
#define WS_CPART 1057024     // conv partials alias the bf16 att/T region (serialized)
// bf16 (ushort), starting at float offset 1057024:
//   attB: 33554432 ushorts (67.1MB)   tB: 33554432 ushorts (67.1MB)

typedef __attribute__((ext_vector_type(8))) short bf16x8;
typedef __attribute__((ext_vector_type(4))) float f32x4;

__device__ __forceinline__ unsigned short f2bf(float f) {
    unsigned int u = __float_as_uint(f);
    u += 0x7FFFu + ((u >> 16) & 1u);          // round-to-nearest-even
    return (unsigned short)(u >> 16);
}
__device__ __forceinline__ float bf2f(unsigned short s) {
    return __uint_as_float(((unsigned int)s) << 16);
}

// K0: scale[o] = conv_g[o] / ||conv_v[o]||
__global__ void k_wnorm(const float* __restrict__ conv_v, const float* __restrict__ conv_g,
                        float* __restrict__ ws) {
    int o = blockIdx.x, t = threadIdx.x;
    const float* v = conv_v + (size_t)o * 2304;
    float s = 0.f;
    for (int i = t; i < 2304; i += 256) { float x = v[i]; s += x * x; }
    for (int off = 1; off < 64; off <<= 1) s += __shfl_xor(s, off, 64);
    __shared__ float red[4];
    if ((t & 63) == 0) red[t >> 6] = s;
    __syncthreads();
    if (t == 0) {
        float tot = red[0] + red[1] + red[2] + red[3];
        ws[WS_SCALE + o] = conv_g[o] / sqrtf(tot);
    }
}

// K1 (MFMA, R22-verified): qkv 1x1 conv as GEMM.
__global__ __launch_bounds__(256) void k_qkv(const float* __restrict__ x,
                                             const float* __restrict__ qkv_w,
                                             const float* __restrict__ qkv_b,
                                             float* __restrict__ ws) {
    int pt = blockIdx.x, ot = blockIdx.y, b = blockIdx.z, t = threadIdx.x;
    int p0 = pt * 64, o0 = ot * 16;
    __shared__ unsigned short aW[16 * 264];      // [o][k pad] 8.4KB
    __shared__ unsigned short xS[64 * 264];      // [px][k pad] 33.8KB
    unsigned int* xU = reinterpret_cast<unsigned int*>(xS);

    for (int idx = t; idx < 4096; idx += 256) {
        int o = idx >> 8, k = idx & 255;
        aW[o * 264 + k] = f2bf(qkv_w[(size_t)(o0 + o) * CINc + k]);
    }
    const float* xb = x + (size_t)b * CINc * LLEN + p0;
    for (int task = t; task < 2048; task += 256) {
        int cpl = task & 15;
        int p4  = (task >> 4) & 15;
        int cph = task >> 8;
        int cp  = cph * 16 + cpl;               // channel pair 0..127
        float4 va = *reinterpret_cast<const float4*>(&xb[(size_t)(2 * cp) * LLEN + p4 * 4]);
        float4 vb = *reinterpret_cast<const float4*>(&xb[(size_t)(2 * cp + 1) * LLEN + p4 * 4]);
        float a0[4] = {va.x, va.y, va.z, va.w};
        float b0[4] = {vb.x, vb.y, vb.z, vb.w};
#pragma unroll
        for (int j = 0; j < 4; j++) {
            unsigned int pk = (unsigned int)f2bf(a0[j]) | ((unsigned int)f2bf(b0[j]) << 16);
            xU[(p4 * 4 + j) * 132 + cp] = pk;
        }
    }
    __syncthreads();

    int lane = t & 63, jg = t >> 6;
    int col = lane & 15, kb = lane >> 4;
    bf16x8 afr[8];
#pragma unroll
    for (int ch = 0; ch < 8; ch++)
        afr[ch] = *reinterpret_cast<const bf16x8*>(&aW[col * 264 + ch * 32 + kb * 8]);
    f32x4 acc = {0.f, 0.f, 0.f, 0.f};
    const unsigned short* xrow = &xS[(jg * 16 + col) * 264];
#pragma unroll
    for (int ch = 0; ch < 8; ch++) {
        bf16x8 bfr = *reinterpret_cast<const bf16x8*>(xrow + ch * 32 + kb * 8);
        acc = __builtin_amdgcn_mfma_f32_16x16x32_bf16(afr[ch], bfr, acc, 0, 0, 0);
    }
    float sc = (ot < 4) ? 0.35355339059327373f : 1.0f;   // DKH^-0.5 on q channels
#pragma unroll
    for (int r = 0; r < 4; r++) {
        int o = o0 + kb * 4 + r;                          // D: row = o, col = px
        float v = (acc[r] + qkv_b[o]) * sc;
        ws[WS_QKV + ((size_t)b * QKVOC + o) * LLEN + p0 + jg * 16 + col] = v;
    }
}

// K2 (MFMA): weight-normed 3x3 conv pass 1 as GEMM (K=288, chunk == tap).
__global__ __launch_bounds__(256) void k_conv(const float* __restrict__ x,
                                              const float* __restrict__ conv_v,
                                              float* __restrict__ ws) {
    int ot = blockIdx.x, z = blockIdx.y, bz = blockIdx.z, t = threadIdx.x;
    int b = bz >> 1, half = bz & 1;
    int o0 = ot * 16, c0 = z * 32, r0 = half * 16;
    __shared__ unsigned short aW[16 * 288];          // A: [o16][k288] bf16 (9KB)
    __shared__ unsigned short xS[18 * 34 * 36];      // X: rows 18 x cols 34 x (32ch+4pad)

    for (int idx = t; idx < 4608; idx += 256) {
        int o = idx / 288, k = idx - o * 288;
        int tap = k >> 5, c = k & 31;
        aW[o * 288 + k] = f2bf(conv_v[((size_t)(o0 + o) * CINc + c0 + c) * 9 + tap]);
    }
    unsigned int* xSu = reinterpret_cast<unsigned int*>(xS);
    for (int i = t; i < 11016; i += 256) xSu[i] = 0u;
    __syncthreads();
    const float* xb = x + ((size_t)b * CINc + c0) * 1024;
    for (int task = t; task < 2304; task += 256) {
        int cp = task & 15;
        int rr = (task >> 4) % 18;
        int wc = task / 288;
        int gr = r0 - 1 + rr;
        int gw = wc * 4;
        if (gr >= 0 && gr < 32) {
            float4 va = *reinterpret_cast<const float4*>(&xb[(size_t)(2 * cp) * 1024 + gr * 32 + gw]);
            float4 vb = *reinterpret_cast<const float4*>(&xb[(size_t)(2 * cp + 1) * 1024 + gr * 32 + gw]);
            int base = (rr * 34 + gw + 1) * 36 + 2 * cp;
            float a0[4] = {va.x, va.y, va.z, va.w};
            float b0[4] = {vb.x, vb.y, vb.z, vb.w};
#pragma unroll
            for (int j = 0; j < 4; j++) {
                unsigned int pk = (unsigned int)f2bf(a0[j]) | ((unsigned int)f2bf(b0[j]) << 16);
                *reinterpret_cast<unsigned int*>(&xS[base + j * 36]) = pk;
            }
        }
    }
    __syncthreads();

    int lane = t & 63, w = t >> 6;
    int col = lane & 15, kb = lane >> 4;
    bf16x8 afr[9];
#pragma unroll
    for (int tap = 0; tap < 9; tap++)
        afr[tap] = *reinterpret_cast<const bf16x8*>(&aW[col * 288 + tap * 32 + kb * 8]);
    char* xb8 = reinterpret_cast<char*>(xS);
#pragma unroll
    for (int tt = 0; tt < 8; tt++) {
        int pt = w * 8 + tt;
        int hl = pt >> 1, w0 = (pt & 1) * 16;
        f32x4 acc = {0.f, 0.f, 0.f, 0.f};
        int pbase = (hl * 34 + w0 + col) * 72 + kb * 16;
#pragma unroll
        for (int tap = 0; tap < 9; tap++) {
            int di = tap / 3, dj = tap % 3;
            bf16x8 bfr = *reinterpret_cast<const bf16x8*>(xb8 + pbase + (di * 34 + dj) * 72);
            acc = __builtin_amdgcn_mfma_f32_16x16x32_bf16(afr[tap], bfr, acc, 0, 0, 0);
        }
        int px = (r0 + hl) * 32 + w0 + col;
#pragma unroll
        for (int r = 0; r < 4; r++) {
            int o = kb * 4 + r;
            ws[WS_CPART + ((size_t)(b * 8 + z) * CONVOC + o0 + o) * 1024 + px] = acc[r];
        }
    }
}

// K2b: reduce 8 channel-chunks, apply weight-norm scale + bias, write 31x31 slice.
__global__ __launch_bounds__(256) void k_convred(const float* __restrict__ conv_b,
                                                 const float* __restrict__ ws,
                                                 float* __restrict__ out) {
    int o = blockIdx.x, b = blockIdx.y, t = threadIdx.x;
    float sc = ws[WS_SCALE + o], bi = conv_b[o];
    for (int px = t; px < 1024; px += 256) {
        float s = 0.f;
#pragma unroll
        for (int z = 0; z < 8; z++)
            s += ws[WS_CPART + ((size_t)(b * 8 + z) * CONVOC + o) * 1024 + px];
        int hh = px >> 5, ww = px & 31;
        if (hh < 31 && ww < 31)
            out[((size_t)(b * 256 + o) * 31 + hh) * 31 + ww] = sc * s + bi;
    }
}

// K3 (register-prefetch, R17-proven): att = 0.5*(qk + rel) + 0.5*prev -> bf16.
// prev loads NONTEMPORAL via ext-vector f32x4 (read-once; keep L2 for att/T/V).
__global__ __launch_bounds__(256, 3) void k_att(const float* __restrict__ ws_,
                                                const float* __restrict__ prev,
                                                const float* __restrict__ rel_k,
                                                unsigned short* __restrict__ attB) {
    int jt = blockIdx.x, it = blockIdx.y, bh = blockIdx.z;
    int b = bh >> 3, h = bh & 7;
    int t = threadIdx.x;
    int i0 = it * 32, j0 = jt * 128;
    int ig = t >> 5, tj = t & 31;

    f32x4 pv[4];
    size_t poff = (((size_t)bh * 1024 + i0 + ig * 4) << 10) + j0 + tj * 4;
#pragma unroll
    for (int ii = 0; ii < 4; ii++)
        pv[ii] = __builtin_nontemporal_load(
            reinterpret_cast<const f32x4*>(&prev[poff + ((size_t)ii << 10)]));
    const float* rbase = rel_k + (size_t)(j0 - i0 + 1020 + 4 * (tj - ig)) * 8;
    float4 ra[7], rb[7];
#pragma unroll
    for (int dgi = 0; dgi < 7; dgi++) {
        ra[dgi] = *reinterpret_cast<const float4*>(rbase + dgi * 8);
        rb[dgi] = *reinterpret_cast<const float4*>(rbase + dgi * 8 + 4);
    }

    __shared__ float kS[8][128];
    __shared__ float qS[32][8];
    const float* qkv = ws_ + WS_QKV;
    const float* qplane = qkv + ((size_t)b * QKVOC + h * 8) * LLEN;       // q[d][i]
    const float* kplane = qkv + ((size_t)b * QKVOC + 64 + h * 8) * LLEN;  // k[d][j]
    {
        int d = t >> 5, jc = (t & 31) * 4;
        *reinterpret_cast<float4*>(&kS[d][jc]) =
            *reinterpret_cast<const float4*>(&kplane[(size_t)d * LLEN + j0 + jc]);
    }
    {
        int i = t >> 3, d = t & 7;
        qS[i][d] = qplane[(size_t)d * LLEN + i0 + i];
    }
    __syncthreads();

    float qr[4][8];
#pragma unroll
    for (int ii = 0; ii < 4; ii++) {
        float4 a = *reinterpret_cast<const float4*>(&qS[ig * 4 + ii][0]);
        float4 c = *reinterpret_cast<const float4*>(&qS[ig * 4 + ii][4]);
        qr[ii][0] = a.x; qr[ii][1] = a.y; qr[ii][2] = a.z; qr[ii][3] = a.w;
        qr[ii][4] = c.x; qr[ii][5] = c.y; qr[ii][6] = c.z; qr[ii][7] = c.w;
    }
    float acc[4][4] = {};
#pragma unroll
    for (int d = 0; d < 8; d++) {
        float4 kv = *reinterpret_cast<const float4*>(&kS[d][tj * 4]);
#pragma unroll
        for (int ii = 0; ii < 4; ii++) {
            float qv = qr[ii][d];
            acc[ii][0] += qv * kv.x; acc[ii][1] += qv * kv.y;
            acc[ii][2] += qv * kv.z; acc[ii][3] += qv * kv.w;
        }
    }
#pragma unroll
    for (int dgi = 0; dgi < 7; dgi++) {
#pragma unroll
        for (int ii = 0; ii < 4; ii++) {
#pragma unroll
            for (int jj = 0; jj < 4; jj++) {
                if (jj - ii + 3 == dgi) {
                    acc[ii][jj] += qr[ii][0] * ra[dgi].x + qr[ii][1] * ra[dgi].y
                                 + qr[ii][2] * ra[dgi].z + qr[ii][3] * ra[dgi].w
                                 + qr[ii][4] * rb[dgi].x + qr[ii][5] * rb[dgi].y
                                 + qr[ii][6] * rb[dgi].z + qr[ii][7] * rb[dgi].w;
                }
            }
        }
    }
#pragma unroll
    for (int ii = 0; ii < 4; ii++) {
        int i = i0 + ig * 4 + ii;
        size_t off = (((size_t)bh * 1024 + i) << 10) + j0 + tj * 4;
        ushort4 o16;
        o16.x = f2bf(0.5f * acc[ii][0] + 0.5f * pv[ii][0]);
        o16.y = f2bf(0.5f * acc[ii][1] + 0.5f * pv[ii][1]);
        o16.z = f2bf(0.5f * acc[ii][2] + 0.5f * pv[ii][2]);
        o16.w = f2bf(0.5f * acc[ii][3] + 0.5f * pv[ii][3]);
        *reinterpret_cast<ushort4*>(&attB[off]) = o16;
    }
}

// K4 (MFMA, R15-verified): 3x3 8->8 head conv over bf16 att as GEMM (K=72 pad 96).
__global__ __launch_bounds__(256) void k_attconv(const unsigned short* __restrict__ attB,
                                                 const float* __restrict__ attc_w,
                                                 const float* __restrict__ attc_b,
                                                 unsigned short* __restrict__ tB,
                                                 float* __restrict__ ws) {
    int jt = blockIdx.x, it = blockIdx.y, b = blockIdx.z, t = threadIdx.x;
    int i0 = it * 16, j0 = jt * 64;
    __shared__ unsigned short aW[16 * 96];            // A: [ho16][k96] bf16 (3KB)
    __shared__ unsigned short xT[18 * 81 * 8];        // X: rows 18, cols 81(80 used), 8 hp
    unsigned int* xU = reinterpret_cast<unsigned int*>(xT);

    for (int idx = t; idx < 1536; idx += 256) {
        int ho = idx / 96, k = idx - ho * 96;
        int tap = k >> 3, hp = k & 7;
        float w = (ho < 8 && tap < 9) ? attc_w[ho * 72 + hp * 9 + tap] : 0.f;
        aW[ho * 96 + k] = f2bf(w);
    }
    const unsigned short* attb = attB + (((size_t)b * 8) << 20);
    for (int task = t; task < 720; task += 256) {
        int r   = task % 18;
        int hpp = (task / 18) & 3;
        int ch  = task / 72;
        int gr  = i0 - 1 + r;
        int gc0 = j0 - 8 + ch * 8;
        uint4 va = make_uint4(0u, 0u, 0u, 0u), vb = va;
        if (gr >= 0 && gr < 1024 && gc0 >= 0 && gc0 < 1024) {
            size_t base = (((size_t)(hpp * 2)) << 20) + ((size_t)gr << 10) + gc0;
            va = *reinterpret_cast<const uint4*>(&attb[base]);
            vb = *reinterpret_cast<const uint4*>(&attb[base + (1u << 20)]);
        }
        int cbase = (r * 81 + ch * 8) * 4 + hpp;
        unsigned int aw[4] = {va.x, va.y, va.z, va.w};
        unsigned int bw[4] = {vb.x, vb.y, vb.z, vb.w};
#pragma unroll
        for (int q = 0; q < 4; q++) {
            xU[cbase + (2 * q) * 4]     = (aw[q] & 0xffffu) | (bw[q] << 16);
            xU[cbase + (2 * q + 1) * 4] = (aw[q] >> 16) | (bw[q] & 0xffff0000u);
        }
    }
    __syncthreads();

    int lane = t & 63, w = t >> 6;
    int col = lane & 15, kb = lane >> 4;      // kb: k-block 0..3
    bf16x8 afr[3];
#pragma unroll
    for (int c = 0; c < 3; c++)
        afr[c] = *reinterpret_cast<const bf16x8*>(&aW[col * 96 + c * 32 + kb * 8]);
    int offs[3];
#pragma unroll
    for (int c = 0; c < 3; c++) {
        int tap = c * 4 + kb;
        int di = (tap < 9) ? tap / 3 : 1;
        int dj = (tap < 9) ? tap % 3 : 1;
        offs[c] = (di * 81 + col + dj + 7) * 16;
    }
    float bias_r[4];
#pragma unroll
    for (int r = 0; r < 4; r++) {
        int ho = kb * 4 + r;
        bias_r[r] = (ho < 8) ? attc_b[ho] : 0.f;
    }
    float ssum = 0.f, ssq = 0.f;
    char* xbyte = reinterpret_cast<char*>(xT);
#pragma unroll
    for (int ri = 0; ri < 4; ri++) {
        int il = w * 4 + ri;                          // local output row
#pragma unroll
        for (int jg = 0; jg < 4; jg++) {
            f32x4 acc = {0.f, 0.f, 0.f, 0.f};
            int base = (il * 81 + jg * 16) * 16;
#pragma unroll
            for (int c = 0; c < 3; c++) {
                bf16x8 bfr = *reinterpret_cast<const bf16x8*>(xbyte + base + offs[c]);
                acc = __builtin_amdgcn_mfma_f32_16x16x32_bf16(afr[c], bfr, acc, 0, 0, 0);
            }
#pragma unroll
            for (int r = 0; r < 4; r++) {
                float v = acc[r] + bias_r[r];
                ssum += v; ssq += v * v;              // pad lanes contribute exact 0
                int ho = kb * 4 + r;
                if (ho < 8) {
                    size_t off = (((size_t)(b * 8 + ho)) << 20) + ((size_t)(i0 + il) << 10)
                               + j0 + jg * 16 + col;
                    tB[off] = f2bf(v);
                }
            }
        }
    }
    for (int off = 1; off < 64; off <<= 1) {
        ssum += __shfl_xor(ssum, off, 64);
        ssq  += __shfl_xor(ssq, off, 64);
    }
    __shared__ float r1[4], r2[4];
    if ((t & 63) == 0) { r1[t >> 6] = ssum; r2[t >> 6] = ssq; }
    __syncthreads();
    if (t == 0) {
        int lin = (b * 64 + it) * 16 + jt;
        ws[WS_PART + lin * 2]     = r1[0] + r1[1] + r1[2] + r1[3];
        ws[WS_PART + lin * 2 + 1] = r2[0] + r2[1] + r2[2] + r2[3];
    }
}

// K4b: reduce partials -> per-batch mean, rstd
__global__ void k_stats(float* __restrict__ ws) {
    int b = blockIdx.x, t = threadIdx.x;
    float S = 0.f, Q = 0.f;
    for (int n = t; n < 1024; n += 256) {
        S += ws[WS_PART + (size_t)(b * 1024 + n) * 2];
        Q += ws[WS_PART + (size_t)(b * 1024 + n) * 2 + 1];
    }
    for (int off = 1; off < 64; off <<= 1) { S += __shfl_xor(S, off, 64); Q += __shfl_xor(Q, off, 64); }
    __shared__ float r1[4], r2[4];
    if ((t & 63) == 0) { r1[t >> 6] = S; r2[t >> 6] = Q; }
    __syncthreads();
    if (t == 0) {
        float Sa = r1[0] + r1[1] + r1[2] + r1[3];
        float Qa = r2[0] + r2[1] + r2[2] + r2[3];
        float N = 8.0f * 1024.f * 1024.f;
        float mean = Sa / N;
        float var = Qa / N - mean * mean;
        ws[WS_STATS + b * 2]     = mean;
        ws[WS_STATS + b * 2 + 1] = 1.0f / sqrtf(var + 1e-5f);
    }
}

// K5 (8 rows/block): V read once for 8 rows (L2 traffic /8); 16 prefetched
// loads in flight; logits stores NONTEMPORAL.  1024 % 8 == 0 -> no straddle.
__global__ __launch_bounds__(256) void k_final(const unsigned short* __restrict__ tB,
                                               const unsigned short* __restrict__ attB,
                                               float* __restrict__ logits,
                                               const float* __restrict__ gn_w,
                                               const float* __restrict__ gn_b,
                                               float* __restrict__ ws) {
    int row0 = blockIdx.x * 8;                  // 8 rows, same (b,h)
    int b = row0 >> 13, h = (row0 >> 10) & 7;
    int t = threadIdx.x;
    float mean = ws[WS_STATS + b * 2], rstd = ws[WS_STATS + b * 2 + 1];
    float gwr = gn_w[h] * rstd;
    float gbm = gn_b[h] - mean * gwr;
    __shared__ float p[8][1024];
    __shared__ float red2[4][8];
    size_t base = (size_t)row0 * 1024 + t * 4;
    ushort4 tv[8], av[8];
#pragma unroll
    for (int r = 0; r < 8; r++) {
        tv[r] = *reinterpret_cast<const ushort4*>(&tB[base + (size_t)r * 1024]);
        av[r] = *reinterpret_cast<const ushort4*>(&attB[base + (size_t)r * 1024]);
    }
    float s[8];
#pragma unroll
    for (int r = 0; r < 8; r++) {
        float tt[4] = {bf2f(tv[r].x), bf2f(tv[r].y), bf2f(tv[r].z), bf2f(tv[r].w)};
        float aa[4] = {bf2f(av[r].x), bf2f(av[r].y), bf2f(av[r].z), bf2f(av[r].w)};
        float lg[4], e[4];
#pragma unroll
        for (int k = 0; k < 4; k++) {
            float xv = tt[k] * gwr + gbm;          // normalize + affine (1 fma)
            xv = fmaxf(xv, 0.01f * xv);            // leaky (branchless)
            lg[k] = 0.5f * xv + 0.5f * aa[k];
            e[k] = __expf(lg[k]);
        }
        f32x4 lgv = {lg[0], lg[1], lg[2], lg[3]};
        __builtin_nontemporal_store(lgv,
            reinterpret_cast<f32x4*>(&logits[base + (size_t)r * 1024]));
        *reinterpret_cast<float4*>(&p[r][t * 4]) = make_float4(e[0], e[1], e[2], e[3]);
        s[r] = (e[0] + e[1]) + (e[2] + e[3]);
    }
#pragma unroll
    for (int off = 1; off < 64; off <<= 1) {
#pragma unroll
        for (int r = 0; r < 8; r++) s[r] += __shfl_xor(s[r], off, 64);
    }
    int wvi = t >> 6, ln = t & 63;
    if (ln == 0) {
#pragma unroll
        for (int r = 0; r < 8; r++) red2[wvi][r] = s[r];
    }
    __syncthreads();
    float sr[8];
#pragma unroll
    for (int r = 0; r < 8; r++)
        sr[r] = (red2[0][r] + red2[1][r]) + (red2[2][r] + red2[3][r]);
    int d = t >> 5, c = t & 31;
    const float* vrow = ws + WS_QKV + ((size_t)b * QKVOC + 128 + h * 8 + d) * LLEN;
    float a[8] = {0.f, 0.f, 0.f, 0.f, 0.f, 0.f, 0.f, 0.f};
#pragma unroll
    for (int u = 0; u < 8; u++) {
        int j = 4 * c + 128 * u;
        float4 vv = *reinterpret_cast<const float4*>(&vrow[j]);
#pragma unroll
        for (int r = 0; r < 8; r++) {
            float4 pv = *reinterpret_cast<const float4*>(&p[r][j]);
            a[r] += pv.x * vv.x + pv.y * vv.y + pv.z * vv.z + pv.w * vv.w;
        }
    }
#pragma unroll
    for (int off = 1; off < 32; off <<= 1) {
#pragma unroll
        for (int r = 0; r < 8; r++) a[r] += __shfl_xor(a[r], off, 64);
    }
    if (c == 0) {
#pragma unroll
        for (int r = 0; r < 8; r++)
            ws[WS_E + (size_t)(row0 + r) * 8 + d] = a[r] / sr[r];
    }
}

// K6: scatter E -> attn output region with the reference's reshape quirk + 31x31 slice
__global__ void k_scatter(const float* __restrict__ ws, float* __restrict__ out) {
    int idx = blockIdx.x * 256 + threadIdx.x;
    if (idx >= 4 * 64 * 31 * 31) return;
    int x = idx % 31; int rest = idx / 31;
    int y = rest % 31; rest /= 31;
    int hd = rest % 64; int b = rest / 64;
    int h = hd >> 3, d = hd & 7;
    int flat = d * 1024 + y * 32 + x;
    int lp = flat >> 3, mp = flat & 7;
    float v = ws[WS_E + ((size_t)(b * 8 + h) * 1024 + lp) * 8 + mp];
    out[((size_t)(b * 256 + 192 + hd) * 31 + y) * 31 + x] = v;
}

extern "C" void kernel_launch(void* const* d_in, const int* in_sizes, int n_in,
                              void* d_out, int out_size, void* d_ws, size_t ws_size,
                              hipStream_t stream) {
    (void)in_sizes; (void)n_in; (void)out_size; (void)ws_size;
    const float* x      = (const float*)d_in[0];
    const float* prev   = (const float*)d_in[1];
    const float* conv_v = (const float*)d_in[2];
    const float* conv_g = (const float*)d_in[3];
    const float* conv_b = (const float*)d_in[4];
    const float* qkv_w  = (const float*)d_in[5];
    const float* qkv_b  = (const float*)d_in[6];
    const float* attc_w = (const float*)d_in[7];
    const float* attc_b = (const float*)d_in[8];
    const float* gn_w   = (const float*)d_in[9];
    const float* gn_b   = (const float*)d_in[10];
    const float* rel_k  = (const float*)d_in[11];
    float* out = (float*)d_out;
    float* ws  = (float*)d_ws;
    float* logits = out + 984064;                          // fp32 output region
    unsigned short* attB = (unsigned short*)(ws + 1057024); // bf16 att (67MB)
    unsigned short* tB   = attB + 33554432;                 // bf16 T   (67MB)

    k_wnorm<<<192, 256, 0, stream>>>(conv_v, conv_g, ws);
    k_qkv<<<dim3(16, 12, 4), 256, 0, stream>>>(x, qkv_w, qkv_b, ws);
    k_conv<<<dim3(12, 8, 8), 256, 0, stream>>>(x, conv_v, ws);
    k_convred<<<dim3(192, 4), 256, 0, stream>>>(conv_b, ws, out);
    k_att<<<dim3(8, 32, 32), 256, 0, stream>>>(ws, prev, rel_k, attB);
    k_attconv<<<dim3(16, 64, 4), 256, 0, stream>>>(attB, attc_w, attc_b, tB, ws);
    k_stats<<<4, 256, 0, stream>>>(ws);
    k_final<<<4096, 256, 0, stream>>>(tB, attB, logits, gn_w, gn_b, ws);
    k_scatter<<<961, 256, 0, stream>>>(ws, out);
}

// Round 24
// 244.874 us; speedup vs baseline: 1.0102x; 1.0102x over previous
//
#include <hip/hip_runtime.h>
#include <math.h>

// ---- problem constants ----
#define NB   4
#define CINc 256
#define LLEN 1024      // H*W = 32*32
#define NHEAD 8
#define QKVOC 192      // 2*DK + DV
#define CONVOC 192     // COUT - DV
#define OHW  31

// ---- workspace layout ----
// floats:
#define WS_SCALE 0           // 192 floats: conv weight-norm scale
#define WS_STATS 192         // 8 floats: per-batch {mean, rstd}
#define WS_PART  256         // 4096*2 floats: per-block conv partial {sum,sumsq}
#define WS_QKV   8448        // 4*192*1024 = 786432 floats
#define WS_E     794880      // 4*8*1024*8 = 262144 floats -> end 1057024
#define WS_CPART 1057024     // conv partials alias the bf16 att/T region (serialized)
// bf16 (ushort), starting at float offset 1057024:
//   attB: 33554432 ushorts (67.1MB)   tB: 33554432 ushorts (67.1MB)

typedef __attribute__((ext_vector_type(8))) short bf16x8;
typedef __attribute__((ext_vector_type(4))) float f32x4;

__device__ __forceinline__ unsigned short f2bf(float f) {
    unsigned int u = __float_as_uint(f);
    u += 0x7FFFu + ((u >> 16) & 1u);          // round-to-nearest-even
    return (unsigned short)(u >> 16);
}
__device__ __forceinline__ float bf2f(unsigned short s) {
    return __uint_as_float(((unsigned int)s) << 16);
}

// K0: scale[o] = conv_g[o] / ||conv_v[o]||
__global__ void k_wnorm(const float* __restrict__ conv_v, const float* __restrict__ conv_g,
                        float* __restrict__ ws) {
    int o = blockIdx.x, t = threadIdx.x;
    const float* v = conv_v + (size_t)o * 2304;
    float s = 0.f;
    for (int i = t; i < 2304; i += 256) { float x = v[i]; s += x * x; }
    for (int off = 1; off < 64; off <<= 1) s += __shfl_xor(s, off, 64);
    __shared__ float red[4];
    if ((t & 63) == 0) red[t >> 6] = s;
    __syncthreads();
    if (t == 0) {
        float tot = red[0] + red[1] + red[2] + red[3];
        ws[WS_SCALE + o] = conv_g[o] / sqrtf(tot);
    }
}

// K1 (MFMA, R22-verified): qkv 1x1 conv as GEMM.
__global__ __launch_bounds__(256) void k_qkv(const float* __restrict__ x,
                                             const float* __restrict__ qkv_w,
                                             const float* __restrict__ qkv_b,
                                             float* __restrict__ ws) {
    int pt = blockIdx.x, ot = blockIdx.y, b = blockIdx.z, t = threadIdx.x;
    int p0 = pt * 64, o0 = ot * 16;
    __shared__ unsigned short aW[16 * 264];      // [o][k pad] 8.4KB
    __shared__ unsigned short xS[64 * 264];      // [px][k pad] 33.8KB
    unsigned int* xU = reinterpret_cast<unsigned int*>(xS);

    for (int idx = t; idx < 4096; idx += 256) {
        int o = idx >> 8, k = idx & 255;
        aW[o * 264 + k] = f2bf(qkv_w[(size_t)(o0 + o) * CINc + k]);
    }
    const float* xb = x + (size_t)b * CINc * LLEN + p0;
    for (int task = t; task < 2048; task += 256) {
        int cpl = task & 15;
        int p4  = (task >> 4) & 15;
        int cph = task >> 8;
        int cp  = cph * 16 + cpl;               // channel pair 0..127
        float4 va = *reinterpret_cast<const float4*>(&xb[(size_t)(2 * cp) * LLEN + p4 * 4]);
        float4 vb = *reinterpret_cast<const float4*>(&xb[(size_t)(2 * cp + 1) * LLEN + p4 * 4]);
        float a0[4] = {va.x, va.y, va.z, va.w};
        float b0[4] = {vb.x, vb.y, vb.z, vb.w};
#pragma unroll
        for (int j = 0; j < 4; j++) {
            unsigned int pk = (unsigned int)f2bf(a0[j]) | ((unsigned int)f2bf(b0[j]) << 16);
            xU[(p4 * 4 + j) * 132 + cp] = pk;
        }
    }
    __syncthreads();

    int lane = t & 63, jg = t >> 6;
    int col = lane & 15, kb = lane >> 4;
    bf16x8 afr[8];
#pragma unroll
    for (int ch = 0; ch < 8; ch++)
        afr[ch] = *reinterpret_cast<const bf16x8*>(&aW[col * 264 + ch * 32 + kb * 8]);
    f32x4 acc = {0.f, 0.f, 0.f, 0.f};
    const unsigned short* xrow = &xS[(jg * 16 + col) * 264];
#pragma unroll
    for (int ch = 0; ch < 8; ch++) {
        bf16x8 bfr = *reinterpret_cast<const bf16x8*>(xrow + ch * 32 + kb * 8);
        acc = __builtin_amdgcn_mfma_f32_16x16x32_bf16(afr[ch], bfr, acc, 0, 0, 0);
    }
    float sc = (ot < 4) ? 0.35355339059327373f : 1.0f;   // DKH^-0.5 on q channels
#pragma unroll
    for (int r = 0; r < 4; r++) {
        int o = o0 + kb * 4 + r;                          // D: row = o, col = px
        float v = (acc[r] + qkv_b[o]) * sc;
        ws[WS_QKV + ((size_t)b * QKVOC + o) * LLEN + p0 + jg * 16 + col] = v;
    }
}

// K2 (MFMA): weight-normed 3x3 conv pass 1 as GEMM (K=288, chunk == tap).
__global__ __launch_bounds__(256) void k_conv(const float* __restrict__ x,
                                              const float* __restrict__ conv_v,
                                              float* __restrict__ ws) {
    int ot = blockIdx.x, z = blockIdx.y, bz = blockIdx.z, t = threadIdx.x;
    int b = bz >> 1, half = bz & 1;
    int o0 = ot * 16, c0 = z * 32, r0 = half * 16;
    __shared__ unsigned short aW[16 * 288];          // A: [o16][k288] bf16 (9KB)
    __shared__ unsigned short xS[18 * 34 * 36];      // X: rows 18 x cols 34 x (32ch+4pad)

    for (int idx = t; idx < 4608; idx += 256) {
        int o = idx / 288, k = idx - o * 288;
        int tap = k >> 5, c = k & 31;
        aW[o * 288 + k] = f2bf(conv_v[((size_t)(o0 + o) * CINc + c0 + c) * 9 + tap]);
    }
    unsigned int* xSu = reinterpret_cast<unsigned int*>(xS);
    for (int i = t; i < 11016; i += 256) xSu[i] = 0u;
    __syncthreads();
    const float* xb = x + ((size_t)b * CINc + c0) * 1024;
    for (int task = t; task < 2304; task += 256) {
        int cp = task & 15;
        int rr = (task >> 4) % 18;
        int wc = task / 288;
        int gr = r0 - 1 + rr;
        int gw = wc * 4;
        if (gr >= 0 && gr < 32) {
            float4 va = *reinterpret_cast<const float4*>(&xb[(size_t)(2 * cp) * 1024 + gr * 32 + gw]);
            float4 vb = *reinterpret_cast<const float4*>(&xb[(size_t)(2 * cp + 1) * 1024 + gr * 32 + gw]);
            int base = (rr * 34 + gw + 1) * 36 + 2 * cp;
            float a0[4] = {va.x, va.y, va.z, va.w};
            float b0[4] = {vb.x, vb.y, vb.z, vb.w};
#pragma unroll
            for (int j = 0; j < 4; j++) {
                unsigned int pk = (unsigned int)f2bf(a0[j]) | ((unsigned int)f2bf(b0[j]) << 16);
                *reinterpret_cast<unsigned int*>(&xS[base + j * 36]) = pk;
            }
        }
    }
    __syncthreads();

    int lane = t & 63, w = t >> 6;
    int col = lane & 15, kb = lane >> 4;
    bf16x8 afr[9];
#pragma unroll
    for (int tap = 0; tap < 9; tap++)
        afr[tap] = *reinterpret_cast<const bf16x8*>(&aW[col * 288 + tap * 32 + kb * 8]);
    char* xb8 = reinterpret_cast<char*>(xS);
#pragma unroll
    for (int tt = 0; tt < 8; tt++) {
        int pt = w * 8 + tt;
        int hl = pt >> 1, w0 = (pt & 1) * 16;
        f32x4 acc = {0.f, 0.f, 0.f, 0.f};
        int pbase = (hl * 34 + w0 + col) * 72 + kb * 16;
#pragma unroll
        for (int tap = 0; tap < 9; tap++) {
            int di = tap / 3, dj = tap % 3;
            bf16x8 bfr = *reinterpret_cast<const bf16x8*>(xb8 + pbase + (di * 34 + dj) * 72);
            acc = __builtin_amdgcn_mfma_f32_16x16x32_bf16(afr[tap], bfr, acc, 0, 0, 0);
        }
        int px = (r0 + hl) * 32 + w0 + col;
#pragma unroll
        for (int r = 0; r < 4; r++) {
            int o = kb * 4 + r;
            ws[WS_CPART + ((size_t)(b * 8 + z) * CONVOC + o0 + o) * 1024 + px] = acc[r];
        }
    }
}

// K2b: reduce 8 channel-chunks, apply weight-norm scale + bias, write 31x31 slice.
__global__ __launch_bounds__(256) void k_convred(const float* __restrict__ conv_b,
                                                 const float* __restrict__ ws,
                                                 float* __restrict__ out) {
    int o = blockIdx.x, b = blockIdx.y, t = threadIdx.x;
    float sc = ws[WS_SCALE + o], bi = conv_b[o];
    for (int px = t; px < 1024; px += 256) {
        float s = 0.f;
#pragma unroll
        for (int z = 0; z < 8; z++)
            s += ws[WS_CPART + ((size_t)(b * 8 + z) * CONVOC + o) * 1024 + px];
        int hh = px >> 5, ww = px & 31;
        if (hh < 31 && ww < 31)
            out[((size_t)(b * 256 + o) * 31 + hh) * 31 + ww] = sc * s + bi;
    }
}

// K3 (register-prefetch, R17-proven): att = 0.5*(qk + rel) + 0.5*prev -> bf16.
// prev loads NONTEMPORAL via ext-vector f32x4 (read-once; keep L2 for att/T/V).
__global__ __launch_bounds__(256, 3) void k_att(const float* __restrict__ ws_,
                                                const float* __restrict__ prev,
                                                const float* __restrict__ rel_k,
                                                unsigned short* __restrict__ attB) {
    int jt = blockIdx.x, it = blockIdx.y, bh = blockIdx.z;
    int b = bh >> 3, h = bh & 7;
    int t = threadIdx.x;
    int i0 = it * 32, j0 = jt * 128;
    int ig = t >> 5, tj = t & 31;

    f32x4 pv[4];
    size_t poff = (((size_t)bh * 1024 + i0 + ig * 4) << 10) + j0 + tj * 4;
#pragma unroll
    for (int ii = 0; ii < 4; ii++)
        pv[ii] = __builtin_nontemporal_load(
            reinterpret_cast<const f32x4*>(&prev[poff + ((size_t)ii << 10)]));
    const float* rbase = rel_k + (size_t)(j0 - i0 + 1020 + 4 * (tj - ig)) * 8;
    float4 ra[7], rb[7];
#pragma unroll
    for (int dgi = 0; dgi < 7; dgi++) {
        ra[dgi] = *reinterpret_cast<const float4*>(rbase + dgi * 8);
        rb[dgi] = *reinterpret_cast<const float4*>(rbase + dgi * 8 + 4);
    }

    __shared__ float kS[8][128];
    __shared__ float qS[32][8];
    const float* qkv = ws_ + WS_QKV;
    const float* qplane = qkv + ((size_t)b * QKVOC + h * 8) * LLEN;       // q[d][i]
    const float* kplane = qkv + ((size_t)b * QKVOC + 64 + h * 8) * LLEN;  // k[d][j]
    {
        int d = t >> 5, jc = (t & 31) * 4;
        *reinterpret_cast<float4*>(&kS[d][jc]) =
            *reinterpret_cast<const float4*>(&kplane[(size_t)d * LLEN + j0 + jc]);
    }
    {
        int i = t >> 3, d = t & 7;
        qS[i][d] = qplane[(size_t)d * LLEN + i0 + i];
    }
    __syncthreads();

    float qr[4][8];
#pragma unroll
    for (int ii = 0; ii < 4; ii++) {
        float4 a = *reinterpret_cast<const float4*>(&qS[ig * 4 + ii][0]);
        float4 c = *reinterpret_cast<const float4*>(&qS[ig * 4 + ii][4]);
        qr[ii][0] = a.x; qr[ii][1] = a.y; qr[ii][2] = a.z; qr[ii][3] = a.w;
        qr[ii][4] = c.x; qr[ii][5] = c.y; qr[ii][6] = c.z; qr[ii][7] = c.w;
    }
    float acc[4][4] = {};
#pragma unroll
    for (int d = 0; d < 8; d++) {
        float4 kv = *reinterpret_cast<const float4*>(&kS[d][tj * 4]);
#pragma unroll
        for (int ii = 0; ii < 4; ii++) {
            float qv = qr[ii][d];
            acc[ii][0] += qv * kv.x; acc[ii][1] += qv * kv.y;
            acc[ii][2] += qv * kv.z; acc[ii][3] += qv * kv.w;
        }
    }
#pragma unroll
    for (int dgi = 0; dgi < 7; dgi++) {
#pragma unroll
        for (int ii = 0; ii < 4; ii++) {
#pragma unroll
            for (int jj = 0; jj < 4; jj++) {
                if (jj - ii + 3 == dgi) {
                    acc[ii][jj] += qr[ii][0] * ra[dgi].x + qr[ii][1] * ra[dgi].y
                                 + qr[ii][2] * ra[dgi].z + qr[ii][3] * ra[dgi].w
                                 + qr[ii][4] * rb[dgi].x + qr[ii][5] * rb[dgi].y
                                 + qr[ii][6] * rb[dgi].z + qr[ii][7] * rb[dgi].w;
                }
            }
        }
    }
#pragma unroll
    for (int ii = 0; ii < 4; ii++) {
        int i = i0 + ig * 4 + ii;
        size_t off = (((size_t)bh * 1024 + i) << 10) + j0 + tj * 4;
        ushort4 o16;
        o16.x = f2bf(0.5f * acc[ii][0] + 0.5f * pv[ii][0]);
        o16.y = f2bf(0.5f * acc[ii][1] + 0.5f * pv[ii][1]);
        o16.z = f2bf(0.5f * acc[ii][2] + 0.5f * pv[ii][2]);
        o16.w = f2bf(0.5f * acc[ii][3] + 0.5f * pv[ii][3]);
        *reinterpret_cast<ushort4*>(&attB[off]) = o16;
    }
}

// K4 (MFMA, R15-verified): 3x3 8->8 head conv over bf16 att as GEMM (K=72 pad 96).
__global__ __launch_bounds__(256) void k_attconv(const unsigned short* __restrict__ attB,
                                                 const float* __restrict__ attc_w,
                                                 const float* __restrict__ attc_b,
                                                 unsigned short* __restrict__ tB,
                                                 float* __restrict__ ws) {
    int jt = blockIdx.x, it = blockIdx.y, b = blockIdx.z, t = threadIdx.x;
    int i0 = it * 16, j0 = jt * 64;
    __shared__ unsigned short aW[16 * 96];            // A: [ho16][k96] bf16 (3KB)
    __shared__ unsigned short xT[18 * 81 * 8];        // X: rows 18, cols 81(80 used), 8 hp
    unsigned int* xU = reinterpret_cast<unsigned int*>(xT);

    for (int idx = t; idx < 1536; idx += 256) {
        int ho = idx / 96, k = idx - ho * 96;
        int tap = k >> 3, hp = k & 7;
        float w = (ho < 8 && tap < 9) ? attc_w[ho * 72 + hp * 9 + tap] : 0.f;
        aW[ho * 96 + k] = f2bf(w);
    }
    const unsigned short* attb = attB + (((size_t)b * 8) << 20);
    for (int task = t; task < 720; task += 256) {
        int r   = task % 18;
        int hpp = (task / 18) & 3;
        int ch  = task / 72;
        int gr  = i0 - 1 + r;
        int gc0 = j0 - 8 + ch * 8;
        uint4 va = make_uint4(0u, 0u, 0u, 0u), vb = va;
        if (gr >= 0 && gr < 1024 && gc0 >= 0 && gc0 < 1024) {
            size_t base = (((size_t)(hpp * 2)) << 20) + ((size_t)gr << 10) + gc0;
            va = *reinterpret_cast<const uint4*>(&attb[base]);
            vb = *reinterpret_cast<const uint4*>(&attb[base + (1u << 20)]);
        }
        int cbase = (r * 81 + ch * 8) * 4 + hpp;
        unsigned int aw[4] = {va.x, va.y, va.z, va.w};
        unsigned int bw[4] = {vb.x, vb.y, vb.z, vb.w};
#pragma unroll
        for (int q = 0; q < 4; q++) {
            xU[cbase + (2 * q) * 4]     = (aw[q] & 0xffffu) | (bw[q] << 16);
            xU[cbase + (2 * q + 1) * 4] = (aw[q] >> 16) | (bw[q] & 0xffff0000u);
        }
    }
    __syncthreads();

    int lane = t & 63, w = t >> 6;
    int col = lane & 15, kb = lane >> 4;      // kb: k-block 0..3
    bf16x8 afr[3];
#pragma unroll
    for (int c = 0; c < 3; c++)
        afr[c] = *reinterpret_cast<const bf16x8*>(&aW[col * 96 + c * 32 + kb * 8]);
    int offs[3];
#pragma unroll
    for (int c = 0; c < 3; c++) {
        int tap = c * 4 + kb;
        int di = (tap < 9) ? tap / 3 : 1;
        int dj = (tap < 9) ? tap % 3 : 1;
        offs[c] = (di * 81 + col + dj + 7) * 16;
    }
    float bias_r[4];
#pragma unroll
    for (int r = 0; r < 4; r++) {
        int ho = kb * 4 + r;
        bias_r[r] = (ho < 8) ? attc_b[ho] : 0.f;
    }
    float ssum = 0.f, ssq = 0.f;
    char* xbyte = reinterpret_cast<char*>(xT);
#pragma unroll
    for (int ri = 0; ri < 4; ri++) {
        int il = w * 4 + ri;                          // local output row
#pragma unroll
        for (int jg = 0; jg < 4; jg++) {
            f32x4 acc = {0.f, 0.f, 0.f, 0.f};
            int base = (il * 81 + jg * 16) * 16;
#pragma unroll
            for (int c = 0; c < 3; c++) {
                bf16x8 bfr = *reinterpret_cast<const bf16x8*>(xbyte + base + offs[c]);
                acc = __builtin_amdgcn_mfma_f32_16x16x32_bf16(afr[c], bfr, acc, 0, 0, 0);
            }
#pragma unroll
            for (int r = 0; r < 4; r++) {
                float v = acc[r] + bias_r[r];
                ssum += v; ssq += v * v;              // pad lanes contribute exact 0
                int ho = kb * 4 + r;
                if (ho < 8) {
                    size_t off = (((size_t)(b * 8 + ho)) << 20) + ((size_t)(i0 + il) << 10)
                               + j0 + jg * 16 + col;
                    tB[off] = f2bf(v);
                }
            }
        }
    }
    for (int off = 1; off < 64; off <<= 1) {
        ssum += __shfl_xor(ssum, off, 64);
        ssq  += __shfl_xor(ssq, off, 64);
    }
    __shared__ float r1[4], r2[4];
    if ((t & 63) == 0) { r1[t >> 6] = ssum; r2[t >> 6] = ssq; }
    __syncthreads();
    if (t == 0) {
        int lin = (b * 64 + it) * 16 + jt;
        ws[WS_PART + lin * 2]     = r1[0] + r1[1] + r1[2] + r1[3];
        ws[WS_PART + lin * 2 + 1] = r2[0] + r2[1] + r2[2] + r2[3];
    }
}

// K4b: reduce partials -> per-batch mean, rstd
__global__ void k_stats(float* __restrict__ ws) {
    int b = blockIdx.x, t = threadIdx.x;
    float S = 0.f, Q = 0.f;
    for (int n = t; n < 1024; n += 256) {
        S += ws[WS_PART + (size_t)(b * 1024 + n) * 2];
        Q += ws[WS_PART + (size_t)(b * 1024 + n) * 2 + 1];
    }
    for (int off = 1; off < 64; off <<= 1) { S += __shfl_xor(S, off, 64); Q += __shfl_xor(Q, off, 64); }
    __shared__ float r1[4], r2[4];
    if ((t & 63) == 0) { r1[t >> 6] = S; r2[t >> 6] = Q; }
    __syncthreads();
    if (t == 0) {
        float Sa = r1[0] + r1[1] + r1[2] + r1[3];
        float Qa = r2[0] + r2[1] + r2[2] + r2[3];
        float N = 8.0f * 1024.f * 1024.f;
        float mean = Sa / N;
        float var = Qa / N - mean * mean;
        ws[WS_STATS + b * 2]     = mean;
        ws[WS_STATS + b * 2 + 1] = 1.0f / sqrtf(var + 1e-5f);
    }
}

// K5 (4 rows/block, R22-proven): prefetched loads, one barrier, V read once
// for 4 rows; logits stores NONTEMPORAL via ext-vector f32x4.
__global__ __launch_bounds__(256) void k_final(const unsigned short* __restrict__ tB,
                                               const unsigned short* __restrict__ attB,
                                               float* __restrict__ logits,
                                               const float* __restrict__ gn_w,
                                               const float* __restrict__ gn_b,
                                               float* __restrict__ ws) {
    int row0 = blockIdx.x * 4;                  // 4 rows, same (b,h): 1024 % 4 == 0
    int b = row0 >> 13, h = (row0 >> 10) & 7;
    int t = threadIdx.x;
    float mean = ws[WS_STATS + b * 2], rstd = ws[WS_STATS + b * 2 + 1];
    float gwr = gn_w[h] * rstd;
    float gbm = gn_b[h] - mean * gwr;
    __shared__ float p[4][1024];
    __shared__ float red2[4][4];
    size_t base = (size_t)row0 * 1024 + t * 4;
    ushort4 tv[4], av[4];
#pragma unroll
    for (int r = 0; r < 4; r++) {
        tv[r] = *reinterpret_cast<const ushort4*>(&tB[base + (size_t)r * 1024]);
        av[r] = *reinterpret_cast<const ushort4*>(&attB[base + (size_t)r * 1024]);
    }
    float s[4];
#pragma unroll
    for (int r = 0; r < 4; r++) {
        float tt[4] = {bf2f(tv[r].x), bf2f(tv[r].y), bf2f(tv[r].z), bf2f(tv[r].w)};
        float aa[4] = {bf2f(av[r].x), bf2f(av[r].y), bf2f(av[r].z), bf2f(av[r].w)};
        float lg[4], e[4];
#pragma unroll
        for (int k = 0; k < 4; k++) {
            float xv = tt[k] * gwr + gbm;          // normalize + affine (1 fma)
            xv = fmaxf(xv, 0.01f * xv);            // leaky (branchless)
            lg[k] = 0.5f * xv + 0.5f * aa[k];
            e[k] = __expf(lg[k]);
        }
        f32x4 lgv = {lg[0], lg[1], lg[2], lg[3]};
        __builtin_nontemporal_store(lgv,
            reinterpret_cast<f32x4*>(&logits[base + (size_t)r * 1024]));
        *reinterpret_cast<float4*>(&p[r][t * 4]) = make_float4(e[0], e[1], e[2], e[3]);
        s[r] = (e[0] + e[1]) + (e[2] + e[3]);
    }
#pragma unroll
    for (int off = 1; off < 64; off <<= 1) {
#pragma unroll
        for (int r = 0; r < 4; r++) s[r] += __shfl_xor(s[r], off, 64);
    }
    int wvi = t >> 6, ln = t & 63;
    if (ln == 0) {
#pragma unroll
        for (int r = 0; r < 4; r++) red2[wvi][r] = s[r];
    }
    __syncthreads();
    float sr[4];
#pragma unroll
    for (int r = 0; r < 4; r++)
        sr[r] = (red2[0][r] + red2[1][r]) + (red2[2][r] + red2[3][r]);
    int d = t >> 5, c = t & 31;
    const float* vrow = ws + WS_QKV + ((size_t)b * QKVOC + 128 + h * 8 + d) * LLEN;
    float a[4] = {0.f, 0.f, 0.f, 0.f};
#pragma unroll
    for (int u = 0; u < 8; u++) {
        int j = 4 * c + 128 * u;
        float4 vv = *reinterpret_cast<const float4*>(&vrow[j]);
#pragma unroll
        for (int r = 0; r < 4; r++) {
            float4 pv = *reinterpret_cast<const float4*>(&p[r][j]);
            a[r] += pv.x * vv.x + pv.y * vv.y + pv.z * vv.z + pv.w * vv.w;
        }
    }
#pragma unroll
    for (int off = 1; off < 32; off <<= 1) {
#pragma unroll
        for (int r = 0; r < 4; r++) a[r] += __shfl_xor(a[r], off, 64);
    }
    if (c == 0) {
#pragma unroll
        for (int r = 0; r < 4; r++)
            ws[WS_E + (size_t)(row0 + r) * 8 + d] = a[r] / sr[r];
    }
}

// K6: scatter E -> attn output region with the reference's reshape quirk + 31x31 slice
__global__ void k_scatter(const float* __restrict__ ws, float* __restrict__ out) {
    int idx = blockIdx.x * 256 + threadIdx.x;
    if (idx >= 4 * 64 * 31 * 31) return;
    int x = idx % 31; int rest = idx / 31;
    int y = rest % 31; rest /= 31;
    int hd = rest % 64; int b = rest / 64;
    int h = hd >> 3, d = hd & 7;
    int flat = d * 1024 + y * 32 + x;
    int lp = flat >> 3, mp = flat & 7;
    float v = ws[WS_E + ((size_t)(b * 8 + h) * 1024 + lp) * 8 + mp];
    out[((size_t)(b * 256 + 192 + hd) * 31 + y) * 31 + x] = v;
}

extern "C" void kernel_launch(void* const* d_in, const int* in_sizes, int n_in,
                              void* d_out, int out_size, void* d_ws, size_t ws_size,
                              hipStream_t stream) {
    (void)in_sizes; (void)n_in; (void)out_size; (void)ws_size;
    const float* x      = (const float*)d_in[0];
    const float* prev   = (const float*)d_in[1];
    const float* conv_v = (const float*)d_in[2];
    const float* conv_g = (const float*)d_in[3];
    const float* conv_b = (const float*)d_in[4];
    const float* qkv_w  = (const float*)d_in[5];
    const float* qkv_b  = (const float*)d_in[6];
    const float* attc_w = (const float*)d_in[7];
    const float* attc_b = (const float*)d_in[8];
    const float* gn_w   = (const float*)d_in[9];
    const float* gn_b   = (const float*)d_in[10];
    const float* rel_k  = (const float*)d_in[11];
    float* out = (float*)d_out;
    float* ws  = (float*)d_ws;
    float* logits = out + 984064;                          // fp32 output region
    unsigned short* attB = (unsigned short*)(ws + 1057024); // bf16 att (67MB)
    unsigned short* tB   = attB + 33554432;                 // bf16 T   (67MB)

    k_wnorm<<<192, 256, 0, stream>>>(conv_v, conv_g, ws);
    k_qkv<<<dim3(16, 12, 4), 256, 0, stream>>>(x, qkv_w, qkv_b, ws);
    k_conv<<<dim3(12, 8, 8), 256, 0, stream>>>(x, conv_v, ws);
    k_convred<<<dim3(192, 4), 256, 0, stream>>>(conv_b, ws, out);
    k_att<<<dim3(8, 32, 32), 256, 0, stream>>>(ws, prev, rel_k, attB);
    k_attconv<<<dim3(16, 64, 4), 256, 0, stream>>>(attB, attc_w, attc_b, tB, ws);
    k_stats<<<4, 256, 0, stream>>>(ws);
    k_final<<<8192, 256, 0, stream>>>(tB, attB, logits, gn_w, gn_b, ws);
    k_scatter<<<961, 256, 0, stream>>>(ws, out);
}